// Round 1
// baseline (2801.004 us; speedup 1.0000x reference)
//
#include <hip/hip_runtime.h>

#define NN 100000
#define NE 1600000
#define D 64

__global__ void deg_kernel(const int* __restrict__ dst, float* __restrict__ deg, int nE) {
    int i = blockIdx.x * blockDim.x + threadIdx.x;
    if (i < nE) atomicAdd(&deg[dst[i]], 1.0f);
}

__global__ void norm_kernel(float* __restrict__ deg, int nN) {
    int i = blockIdx.x * blockDim.x + threadIdx.x;
    if (i < nN) deg[i] = rsqrtf(fmaxf(deg[i], 1.0f));
}

// One thread handles 4 contiguous features of one edge (16 threads/edge).
// POW=1: w = norm[s]   (hop 1, reads raw feat)
// POW=2: w = norm[s]^2 (hop 2, folds post-norm of hop1 + pre-norm of hop2)
template <int POW>
__global__ void scatter_kernel(const float* __restrict__ in,
                               const int* __restrict__ src,
                               const int* __restrict__ dst,
                               const float* __restrict__ norm,
                               float* __restrict__ out, int nE) {
    long long t = (long long)blockIdx.x * blockDim.x + threadIdx.x;
    int e = (int)(t >> 4);
    int c = (int)(t & 15);
    if (e >= nE) return;
    int s = src[e];
    int d = dst[e];
    float w = norm[s];
    if (POW == 2) w *= w;
    const float4 v = *reinterpret_cast<const float4*>(in + (size_t)s * D + c * 4);
    float* o = out + (size_t)d * D + c * 4;
    atomicAdd(o + 0, v.x * w);
    atomicAdd(o + 1, v.y * w);
    atomicAdd(o + 2, v.z * w);
    atomicAdd(o + 3, v.w * w);
}

// out row n = (norm[n] * S2[n,:]) @ W1^T + b1, in place on d_out.
// Block = 256 threads = 4 rows x 64 cols. Stage rows + W1 in LDS, sync, compute.
__global__ __launch_bounds__(256) void fc_kernel(float* __restrict__ h,
                                                 const float* __restrict__ norm,
                                                 const float* __restrict__ W1,
                                                 const float* __restrict__ b1) {
    __shared__ float shW[D][D + 1];  // +1 pad: lane-varying j at stride 65 -> 2-way (free)
    __shared__ float shX[4][D];
    int tid = threadIdx.x;
    for (int i = tid; i < D * D; i += 256) shW[i / D][i % D] = W1[i];
    int r = tid / D;       // 0..3 (row within block) == wave id
    int j = tid % D;       // 0..63 (output feature) == lane
    int n = blockIdx.x * 4 + r;
    shX[r][j] = h[(size_t)n * D + j] * norm[n];
    __syncthreads();
    float acc = b1[j];
#pragma unroll
    for (int k = 0; k < D; ++k) acc += shX[r][k] * shW[j][k];
    h[(size_t)n * D + j] = acc;
}

extern "C" void kernel_launch(void* const* d_in, const int* in_sizes, int n_in,
                              void* d_out, int out_size, void* d_ws, size_t ws_size,
                              hipStream_t stream) {
    const float* feat = (const float*)d_in[0];
    const int* src    = (const int*)d_in[1];
    const int* dst    = (const int*)d_in[2];
    const float* W1   = (const float*)d_in[3];
    const float* b1   = (const float*)d_in[4];
    float* out        = (float*)d_out;

    // ws layout: [norm: NN floats][buf1: NN*D floats]  (~26 MB)
    float* norm = (float*)d_ws;
    float* buf1 = norm + NN;

    hipMemsetAsync(d_ws, 0, (size_t)NN * (1 + D) * sizeof(float), stream);
    hipMemsetAsync(d_out, 0, (size_t)NN * D * sizeof(float), stream);

    deg_kernel<<<(NE + 255) / 256, 256, 0, stream>>>(dst, norm, NE);
    norm_kernel<<<(NN + 255) / 256, 256, 0, stream>>>(norm, NN);

    const int sthreads = NE * 16;
    scatter_kernel<1><<<(sthreads + 255) / 256, 256, 0, stream>>>(feat, src, dst, norm, buf1, NE);
    scatter_kernel<2><<<(sthreads + 255) / 256, 256, 0, stream>>>(buf1, src, dst, norm, out, NE);

    fc_kernel<<<NN / 4, 256, 0, stream>>>(out, norm, W1, b1);
}

// Round 2
// 549.018 us; speedup vs baseline: 5.1018x; 5.1018x over previous
//
#include <hip/hip_runtime.h>

#define NN 100000
#define NE 1600000
#define D 64

// ---------- CSR build ----------

__global__ void deg_kernel(const int* __restrict__ dst, int* __restrict__ deg, int nE) {
    int i = blockIdx.x * blockDim.x + threadIdx.x;
    if (i < nE) atomicAdd(&deg[dst[i]], 1);
}

// Single-block exclusive scan of deg[0..NN) -> rowptr[0..NN], rowptr[NN]=NE.
__global__ __launch_bounds__(1024) void scan_kernel(const int* __restrict__ deg,
                                                    int* __restrict__ rowptr) {
    __shared__ int sums[1024];
    const int t = threadIdx.x;
    const int CH = (NN + 1023) / 1024;  // 98
    const int b = t * CH;
    const int e = min(b + CH, NN);
    int s = 0;
    for (int i = b; i < e; ++i) s += deg[i];
    sums[t] = s;
    __syncthreads();
    // Hillis-Steele inclusive scan over the 1024 chunk sums
    for (int off = 1; off < 1024; off <<= 1) {
        int v = (t >= off) ? sums[t - off] : 0;
        __syncthreads();
        sums[t] += v;
        __syncthreads();
    }
    int excl = (t == 0) ? 0 : sums[t - 1];
    for (int i = b; i < e; ++i) { rowptr[i] = excl; excl += deg[i]; }
    if (t == 1023) rowptr[NN] = excl;  // == NE
}

__global__ void fill_kernel(const int* __restrict__ src, const int* __restrict__ dst,
                            const int* __restrict__ rowptr, int* __restrict__ cursor,
                            int* __restrict__ csr_src, int nE) {
    int i = blockIdx.x * blockDim.x + threadIdx.x;
    if (i < nE) {
        int d = dst[i];
        int p = rowptr[d] + atomicAdd(&cursor[d], 1);
        csr_src[p] = src[i];
    }
}

__global__ void norm_kernel(const int* __restrict__ deg, float* __restrict__ norm, int nN) {
    int i = blockIdx.x * blockDim.x + threadIdx.x;
    if (i < nN) norm[i] = rsqrtf(fmaxf((float)deg[i], 1.0f));
}

// ---------- Gather-side aggregation: one wave per dst node, lane = feature ----------
// POW=1: out[d,j] = sum_e norm[s]   * in[s,j]
// POW=2: out[d,j] = sum_e norm[s]^2 * in[s,j]
template <int POW>
__global__ __launch_bounds__(256) void gather_kernel(const float* __restrict__ in,
                                                     const int* __restrict__ rowptr,
                                                     const int* __restrict__ csr_src,
                                                     const float* __restrict__ norm,
                                                     float* __restrict__ out, int nN) {
    int node = blockIdx.x * 4 + (threadIdx.x >> 6);
    int lane = threadIdx.x & 63;
    if (node >= nN) return;
    int e = rowptr[node];
    const int end = rowptr[node + 1];
    float acc = 0.0f;
    // unroll-by-4 for memory-level parallelism (independent dependent-load chains)
    for (; e + 3 < end; e += 4) {
        int s0 = csr_src[e + 0], s1 = csr_src[e + 1];
        int s2 = csr_src[e + 2], s3 = csr_src[e + 3];
        float w0 = norm[s0], w1 = norm[s1], w2 = norm[s2], w3 = norm[s3];
        if (POW == 2) { w0 *= w0; w1 *= w1; w2 *= w2; w3 *= w3; }
        float v0 = in[(size_t)s0 * D + lane];
        float v1 = in[(size_t)s1 * D + lane];
        float v2 = in[(size_t)s2 * D + lane];
        float v3 = in[(size_t)s3 * D + lane];
        acc += w0 * v0 + w1 * v1 + w2 * v2 + w3 * v3;
    }
    for (; e < end; ++e) {
        int s = csr_src[e];
        float w = norm[s];
        if (POW == 2) w *= w;
        acc += w * in[(size_t)s * D + lane];
    }
    out[(size_t)node * D + lane] = acc;
}

// ---------- Fused final norm + FC:  h[n,:] = (norm[n]*h[n,:]) @ W1^T + b1 ----------
__global__ __launch_bounds__(256) void fc_kernel(float* __restrict__ h,
                                                 const float* __restrict__ norm,
                                                 const float* __restrict__ W1,
                                                 const float* __restrict__ b1) {
    __shared__ float shW[D][D + 1];
    __shared__ float shX[4][D];
    int tid = threadIdx.x;
    for (int i = tid; i < D * D; i += 256) shW[i / D][i % D] = W1[i];
    int r = tid / D;
    int j = tid % D;
    int n = blockIdx.x * 4 + r;
    shX[r][j] = h[(size_t)n * D + j] * norm[n];
    __syncthreads();
    float acc = b1[j];
#pragma unroll
    for (int k = 0; k < D; ++k) acc += shX[r][k] * shW[j][k];
    h[(size_t)n * D + j] = acc;
}

extern "C" void kernel_launch(void* const* d_in, const int* in_sizes, int n_in,
                              void* d_out, int out_size, void* d_ws, size_t ws_size,
                              hipStream_t stream) {
    const float* feat = (const float*)d_in[0];
    const int* src    = (const int*)d_in[1];
    const int* dst    = (const int*)d_in[2];
    const float* W1   = (const float*)d_in[3];
    const float* b1   = (const float*)d_in[4];
    float* out        = (float*)d_out;

    // ws layout (4B units): deg[NN] | rowptr[NN+1] | cursor[NN] | norm[NN] | csr_src[NE] | t1[NN*D]
    int*   deg     = (int*)d_ws;
    int*   rowptr  = deg + NN;
    int*   cursor  = rowptr + NN + 1;
    float* norm    = (float*)(cursor + NN);
    int*   csr_src = (int*)(norm + NN);
    float* t1      = (float*)(csr_src + NE);
    // total ~33.2 MB

    // zero deg + rowptr + cursor in one shot (rowptr is rewritten by scan anyway)
    hipMemsetAsync(d_ws, 0, (size_t)(3 * NN + 1) * sizeof(int), stream);

    deg_kernel<<<(NE + 255) / 256, 256, 0, stream>>>(dst, deg, NE);
    scan_kernel<<<1, 1024, 0, stream>>>(deg, rowptr);
    fill_kernel<<<(NE + 255) / 256, 256, 0, stream>>>(src, dst, rowptr, cursor, csr_src, NE);
    norm_kernel<<<(NN + 255) / 256, 256, 0, stream>>>(deg, norm, NN);

    // hop 1: t1[d] = sum norm[s] * feat[s]
    gather_kernel<1><<<(NN + 3) / 4, 256, 0, stream>>>(feat, rowptr, csr_src, norm, t1, NN);
    // hop 2: out[d] = sum norm[s]^2 * t1[s]
    gather_kernel<2><<<(NN + 3) / 4, 256, 0, stream>>>(t1, rowptr, csr_src, norm, out, NN);

    // final: out[n] = (norm[n]*out[n]) @ W1^T + b1, in place
    fc_kernel<<<NN / 4, 256, 0, stream>>>(out, norm, W1, b1);
}

// Round 3
// 402.736 us; speedup vs baseline: 6.9549x; 1.3632x over previous
//
#include <hip/hip_runtime.h>

#define NN 100000
#define NE 1600000
#define D 64
#define SCAN_B 1024
#define NBLK ((NN + SCAN_B - 1) / SCAN_B)  // 98

// ---------- CSR build ----------

__global__ void deg_kernel(const int* __restrict__ dst, int* __restrict__ deg, int nE) {
    int i = blockIdx.x * blockDim.x + threadIdx.x;
    if (i < nE) atomicAdd(&deg[dst[i]], 1);
}

// Hierarchical exclusive scan of deg -> rowptr.
__global__ __launch_bounds__(1024) void scan1_kernel(const int* __restrict__ deg,
                                                     int* __restrict__ rowptr,
                                                     int* __restrict__ bsums) {
    __shared__ int tmp[SCAN_B];
    int t = threadIdx.x;
    int g = blockIdx.x * SCAN_B + t;
    int v = (g < NN) ? deg[g] : 0;
    int x = v;
    tmp[t] = x;
    __syncthreads();
    for (int off = 1; off < SCAN_B; off <<= 1) {
        int y = (t >= off) ? tmp[t - off] : 0;
        __syncthreads();
        x += y;
        tmp[t] = x;
        __syncthreads();
    }
    if (g < NN) rowptr[g] = x - v;          // exclusive within block
    if (t == SCAN_B - 1) bsums[blockIdx.x] = x;  // block total
}

__global__ __launch_bounds__(128) void scan2_kernel(int* __restrict__ bsums) {
    __shared__ int tmp[128];
    int t = threadIdx.x;
    int v = (t < NBLK) ? bsums[t] : 0;
    int x = v;
    tmp[t] = x;
    __syncthreads();
    for (int off = 1; off < 128; off <<= 1) {
        int y = (t >= off) ? tmp[t - off] : 0;
        __syncthreads();
        x += y;
        tmp[t] = x;
        __syncthreads();
    }
    if (t < NBLK) bsums[t] = x - v;  // exclusive block offsets
}

__global__ __launch_bounds__(1024) void scan3_kernel(int* __restrict__ rowptr,
                                                     const int* __restrict__ bsums) {
    int g = blockIdx.x * SCAN_B + threadIdx.x;
    if (g < NN) rowptr[g] += bsums[blockIdx.x];
    if (g == 0) rowptr[NN] = NE;
}

__global__ void fill_kernel(const int* __restrict__ src, const int* __restrict__ dst,
                            const int* __restrict__ rowptr, int* __restrict__ cursor,
                            int* __restrict__ csr_src, int nE) {
    int i = blockIdx.x * blockDim.x + threadIdx.x;
    if (i < nE) {
        int d = dst[i];
        int p = rowptr[d] + atomicAdd(&cursor[d], 1);
        csr_src[p] = src[i];
    }
}

__global__ void norm_kernel(const int* __restrict__ deg, float* __restrict__ norm, int nN) {
    int i = blockIdx.x * blockDim.x + threadIdx.x;
    if (i < nN) norm[i] = rsqrtf(fmaxf((float)deg[i], 1.0f));
}

// ---------- Gather-side aggregation: one wave per dst node, lane = feature ----------
// HOP=1: out[d,j] = norm[d]^2 * sum_e norm[s] * in[s,j]   (post-scale folded in)
// HOP=2: out[d,j] = sum_e in[s,j]                          (weights pre-folded)
template <int HOP>
__global__ __launch_bounds__(256) void gather_kernel(const float* __restrict__ in,
                                                     const int* __restrict__ rowptr,
                                                     const int* __restrict__ csr_src,
                                                     const float* __restrict__ norm,
                                                     float* __restrict__ out, int nN) {
    int node = blockIdx.x * 4 + (threadIdx.x >> 6);
    int lane = threadIdx.x & 63;
    if (node >= nN) return;
    int e = rowptr[node];
    const int end = rowptr[node + 1];
    float acc = 0.0f;
    for (; e + 7 < end; e += 8) {
#pragma unroll
        for (int u = 0; u < 8; ++u) {
            int s = csr_src[e + u];
            float v = in[(size_t)s * D + lane];
            if (HOP == 1) v *= norm[s];
            acc += v;
        }
    }
    for (; e < end; ++e) {
        int s = csr_src[e];
        float v = in[(size_t)s * D + lane];
        if (HOP == 1) v *= norm[s];
        acc += v;
    }
    if (HOP == 1) {
        float nd = norm[node];
        acc *= nd * nd;
    }
    out[(size_t)node * D + lane] = acc;
}

// ---------- Fused final norm + FC:  h[n,:] = (norm[n]*h[n,:]) @ W1^T + b1 ----------
__global__ __launch_bounds__(256) void fc_kernel(float* __restrict__ h,
                                                 const float* __restrict__ norm,
                                                 const float* __restrict__ W1,
                                                 const float* __restrict__ b1) {
    __shared__ float shW[D][D + 1];
    __shared__ float shX[4][D];
    int tid = threadIdx.x;
    for (int i = tid; i < D * D; i += 256) shW[i / D][i % D] = W1[i];
    int r = tid / D;
    int j = tid % D;
    int n = blockIdx.x * 4 + r;
    shX[r][j] = h[(size_t)n * D + j] * norm[n];
    __syncthreads();
    float acc = b1[j];
#pragma unroll
    for (int k = 0; k < D; ++k) acc += shX[r][k] * shW[j][k];
    h[(size_t)n * D + j] = acc;
}

extern "C" void kernel_launch(void* const* d_in, const int* in_sizes, int n_in,
                              void* d_out, int out_size, void* d_ws, size_t ws_size,
                              hipStream_t stream) {
    const float* feat = (const float*)d_in[0];
    const int* src    = (const int*)d_in[1];
    const int* dst    = (const int*)d_in[2];
    const float* W1   = (const float*)d_in[3];
    const float* b1   = (const float*)d_in[4];
    float* out        = (float*)d_out;

    // ws layout (4B units):
    // deg[NN] | rowptr[NN+1] | cursor[NN] | norm[NN] | bsums[NBLK] | csr_src[NE] | t1[NN*D]
    int*   deg     = (int*)d_ws;
    int*   rowptr  = deg + NN;
    int*   cursor  = rowptr + NN + 1;
    float* norm    = (float*)(cursor + NN);
    int*   bsums   = (int*)(norm + NN);
    int*   csr_src = bsums + NBLK;
    float* t1      = (float*)(csr_src + NE);

    // zero deg + rowptr + cursor (contiguous leading region)
    hipMemsetAsync(d_ws, 0, (size_t)(3 * NN + 1) * sizeof(int), stream);

    deg_kernel<<<(NE + 255) / 256, 256, 0, stream>>>(dst, deg, NE);
    scan1_kernel<<<NBLK, SCAN_B, 0, stream>>>(deg, rowptr, bsums);
    scan2_kernel<<<1, 128, 0, stream>>>(bsums);
    scan3_kernel<<<NBLK, SCAN_B, 0, stream>>>(rowptr, bsums);
    fill_kernel<<<(NE + 255) / 256, 256, 0, stream>>>(src, dst, rowptr, cursor, csr_src, NE);
    norm_kernel<<<(NN + 255) / 256, 256, 0, stream>>>(deg, norm, NN);

    // hop 1: t1[d] = norm[d]^2 * sum norm[s] * feat[s]
    gather_kernel<1><<<(NN + 3) / 4, 256, 0, stream>>>(feat, rowptr, csr_src, norm, t1, NN);
    // hop 2: out[d] = sum t1[s]
    gather_kernel<2><<<(NN + 3) / 4, 256, 0, stream>>>(t1, rowptr, csr_src, norm, out, NN);

    // final: out[n] = (norm[n]*out[n]) @ W1^T + b1, in place
    fc_kernel<<<NN / 4, 256, 0, stream>>>(out, norm, W1, b1);
}